// Round 1
// 344.501 us; speedup vs baseline: 1.0274x; 1.0274x over previous
//
#include <hip/hip_runtime.h>
#include <math.h>

#define N_   64
#define C_   512
#define HW_  1024
#define K_   64
#define ALPHA_ 50.0f
#define EPS_  1e-12f

// d_out float offsets
#define OUT_VLAD 0
#define OUT_SA   2097152     // N*K*C
#define OUT_FEAT 6291456     // + N*K*HW

// ws byte offsets (~25.9 MB, well under proven 50.6 MB)
#define WSB_WT    0           // fp32 [K][C]           131072 B
#define WSB_WNTB  131072      // bf16 [K][C]            65536 B
#define WSB_INVN  196608      // fp32 [N][HW]          262144 B
#define WSB_A     458752      // bf16 [N][K][HW]      8388608 B
#define WSB_SAP   8847360     // fp32 [N][16][K]       262144 B  (sumA partials)
#define WSB_PART  9109504     // fp32 2x[N][K][C]    16777216 B
#define PART_ELEMS 2097152    // floats per partial copy

typedef __attribute__((ext_vector_type(8))) __bf16 bf16x8;
typedef __attribute__((ext_vector_type(4))) float f32x4;
typedef __attribute__((ext_vector_type(8))) unsigned short ushort8v;

__device__ inline unsigned short f2bf(float f) {
    unsigned int u = __builtin_bit_cast(unsigned int, f);
    u = (u + 0x7FFFu + ((u >> 16) & 1u)) >> 16;
    return (unsigned short)u;
}
__device__ inline float bf2f(unsigned short h) {
    unsigned int u = ((unsigned int)h) << 16;
    return __builtin_bit_cast(float, u);
}
__device__ inline f32x4 mfma16(const unsigned short* pa, const unsigned short* pb, f32x4 c) {
    bf16x8 a = *(const bf16x8*)pa;
    bf16x8 b = *(const bf16x8*)pb;
    return __builtin_amdgcn_mfma_f32_16x16x32_bf16(a, b, c, 0, 0, 0);
}

// ---------------- K1: weight column norms -> wT fp32, wnTb bf16, both [K][C]
__global__ __launch_bounds__(256) void k1_weights(const float* __restrict__ W,
                                                  float* __restrict__ wT,
                                                  unsigned short* __restrict__ wnTb) {
    int k = blockIdx.x;
    int t = threadIdx.x;
    __shared__ float red[256];
    float s = 0.f;
    for (int c = t; c < C_; c += 256) { float w = W[c * K_ + k]; s += w * w; }
    red[t] = s;
    __syncthreads();
    for (int st = 128; st > 0; st >>= 1) {
        if (t < st) red[t] += red[t + st];
        __syncthreads();
    }
    float inv = 1.f / fmaxf(sqrtf(red[0]), EPS_);
    for (int c = t; c < C_; c += 256) {
        float w = W[c * K_ + k];
        wT[k * C_ + c]   = w;
        wnTb[k * C_ + c] = f2bf(w * inv);
    }
}

// ---------------- K2: L2-normalize x over C, write feature [N][HW][C] + invn
__global__ __launch_bounds__(256) void k2_normfeat(const float* __restrict__ x,
                                                   float* __restrict__ out,
                                                   float* __restrict__ invn) {
    float* feat = out + OUT_FEAT;
    int b   = blockIdx.x;
    int n   = b >> 6;
    int hw0 = (b & 63) << 4;
    int t   = threadIdx.x;
    __shared__ float Xs[C_ * 17 + 256 + 16];
    float* red = Xs + C_ * 17;
    float* nrm = red + 256;
    const float* xn = x + (long)n * C_ * HW_;
    for (int j = 0; j < 32; ++j) {
        int idx = j * 256 + t;
        int c = idx >> 4, p = idx & 15;
        Xs[c * 17 + p] = xn[c * HW_ + hw0 + p];
    }
    __syncthreads();
    {
        int p = t & 15, cg = t >> 4;
        float s = 0.f;
        for (int j = 0; j < 32; ++j) {
            float v = Xs[(cg + 16 * j) * 17 + p];
            s += v * v;
        }
        red[t] = s;
    }
    __syncthreads();
    if (t < 16) {
        float s = 0.f;
        for (int g = 0; g < 16; ++g) s += red[g * 16 + t];
        float iv = 1.f / fmaxf(sqrtf(s), EPS_);
        nrm[t] = iv;
        invn[(long)n * HW_ + hw0 + t] = iv;
    }
    __syncthreads();
    float* frow = feat + ((long)n * HW_ + hw0) * C_;
    for (int p = 0; p < 16; ++p) {
        float iv = nrm[p];
        frow[(long)p * C_ + t]       = Xs[t * 17 + p] * iv;
        frow[(long)p * C_ + t + 256] = Xs[(t + 256) * 17 + p] * iv;
    }
}

// ---------------- K3: MFMA GEMM1 (logits = feat . WnT) + softmax -> sa, A(bf16)
// 64-pixel tiles, grid = 64n x 16 tiles = 1024 blocks -> 4 blocks/CU.
// Also folds sumA partial reduction (kills old K3b kernel).
#define K3PITCH 136   // bf16 elems; 272 B row, 16B aligned, balanced banks
__global__ __launch_bounds__(256, 4) void k3_sa(const float* __restrict__ feat,
                                                const unsigned short* __restrict__ wnTb,
                                                const float* __restrict__ bias,
                                                float* __restrict__ sa,
                                                unsigned short* __restrict__ Ab,
                                                float* __restrict__ sumA_part) {
    __shared__ alignas(16) unsigned short sm[64 * K3PITCH + 64 * K3PITCH]; // 34816 B
    unsigned short* Fsh = sm;                  // [64 p][128 c] per chunk
    unsigned short* Wsh = sm + 64 * K3PITCH;   // [64 k][128 c] per chunk
    // phase-2 overlay (19712 B < 34816 B)
    float* Ls = (float*)sm;        // [64 kc][66 p-pitch]
    float* Bz = Ls + 64 * 66;      // [64]
    float* Zm = Bz + 64;           // [64]
    float* Iv = Zm + 64;           // [64]
    float* Rm = Iv + 64;           // [4][64]
    float* Rs = Rm + 256;          // [4][64]

    int b    = blockIdx.x;
    int n    = b >> 4;
    int tile = b & 15;
    int hw0  = tile << 6;
    int t    = threadIdx.x;
    int l    = t & 63, w = t >> 6;
    int mr   = l & 15, q = l >> 4;

    f32x4 acc[4];
#pragma unroll
    for (int j = 0; j < 4; ++j) acc[j] = (f32x4){0.f, 0.f, 0.f, 0.f};

    const float* fb = feat + ((long)n * HW_ + hw0) * C_;
    for (int ch = 0; ch < 4; ++ch) {
        int c0 = ch * 128;
        __syncthreads();
#pragma unroll
        for (int j = 0; j < 4; ++j) {          // Fsh: 64p x 128c (cvt fp32->bf16)
            int idx = j * 256 + t;
            int row = idx >> 4, sg = idx & 15;
            const float* src = fb + (long)row * C_ + c0 + sg * 8;
            float4 v0 = *(const float4*)src;
            float4 v1 = *(const float4*)(src + 4);
            ushort8v pk;
            pk[0] = f2bf(v0.x); pk[1] = f2bf(v0.y); pk[2] = f2bf(v0.z); pk[3] = f2bf(v0.w);
            pk[4] = f2bf(v1.x); pk[5] = f2bf(v1.y); pk[6] = f2bf(v1.z); pk[7] = f2bf(v1.w);
            *(ushort8v*)(Fsh + row * K3PITCH + sg * 8) = pk;
        }
#pragma unroll
        for (int j = 0; j < 4; ++j) {          // Wsh: 64k x 128c (bf16 copy)
            int idx = j * 256 + t;
            int row = idx >> 4, sg = idx & 15;
            *(uint4*)(Wsh + row * K3PITCH + sg * 8) =
                *(const uint4*)(wnTb + row * C_ + c0 + sg * 8);
        }
        __syncthreads();
#pragma unroll
        for (int ks = 0; ks < 4; ++ks) {
            int ko = ks * 32 + q * 8;
            const unsigned short* ap = Fsh + (w * 16 + mr) * K3PITCH + ko;
#pragma unroll
            for (int j = 0; j < 4; ++j) {
                const unsigned short* bp = Wsh + (j * 16 + mr) * K3PITCH + ko;
                acc[j] = mfma16(ap, bp, acc[j]);
            }
        }
    }
    __syncthreads();
    // dump logits: acc[j][r] = logit(p = w*16 + q*4 + r, k = j*16 + mr)
#pragma unroll
    for (int j = 0; j < 4; ++j)
#pragma unroll
        for (int r = 0; r < 4; ++r)
            Ls[(j * 16 + mr) * 66 + w * 16 + q * 4 + r] = acc[j][r];
    if (t < 64) Bz[t] = bias[t];
    __syncthreads();
    // softmax over kc (64) per pixel p (64), all 256 threads active
    {
        int p = t & 63, g = t >> 6;
        float mx = -1e30f;
#pragma unroll
        for (int kk = 0; kk < 16; ++kk) {
            int kc = g * 16 + kk;
            float z = (Ls[kc * 66 + p] + Bz[kc]) * ALPHA_;
            mx = fmaxf(mx, z);
        }
        Rm[g * 64 + p] = mx;
        __syncthreads();
        float M = fmaxf(fmaxf(Rm[p], Rm[64 + p]), fmaxf(Rm[128 + p], Rm[192 + p]));
        float s = 0.f;
#pragma unroll
        for (int kk = 0; kk < 16; ++kk) {
            int kc = g * 16 + kk;
            float z = (Ls[kc * 66 + p] + Bz[kc]) * ALPHA_;
            s += __expf(z - M);
        }
        Rs[g * 64 + p] = s;
        __syncthreads();
        if (g == 0) {
            Zm[p] = M;
            Iv[p] = 1.f / (Rs[p] + Rs[64 + p] + Rs[128 + p] + Rs[192 + p]);
        }
    }
    __syncthreads();
    float* sab = sa + (long)n * K_ * HW_ + hw0;
    unsigned short* Arow = Ab + (long)n * K_ * HW_ + hw0;
#pragma unroll
    for (int j = 0; j < 16; ++j) {
        int idx = j * 256 + t;
        int kc = idx >> 6, p = idx & 63;
        float v = Ls[kc * 66 + p];
        sab[(long)kc * HW_ + p] = v;
        float a = __expf((v + Bz[kc]) * ALPHA_ - Zm[p]) * Iv[p];
        Arow[(long)kc * HW_ + p] = f2bf(a);
        Ls[kc * 66 + p] = a;               // overwrite logit with a for reduction
    }
    __syncthreads();
    if (t < 64) {                          // per-block partial sumA over 64 pixels
        float s = 0.f;
        for (int p2 = 0; p2 < 64; ++p2) s += Ls[t * 66 + p2];
        sumA_part[((long)n * 16 + tile) * 64 + t] = s;
    }
}

// ---------------- K4: MFMA GEMM2 vlad_raw = A . feat  (B from x*invn)
// 64-c tiles, grid = 64n x (8 c-tiles x 2 h-halves) = 1024 blocks -> 4 blocks/CU.
#define K4PITCH 72    // bf16; 144 B rows, 16B aligned
__global__ __launch_bounds__(256, 4) void k4_vlad(const float* __restrict__ x,
                                                  const float* __restrict__ invn,
                                                  const unsigned short* __restrict__ Ab,
                                                  float* __restrict__ part) {
    __shared__ float invs[512];
    __shared__ alignas(16) unsigned short Ash[64 * K4PITCH];    // 9216 B
    __shared__ alignas(16) unsigned short Fsh[64 * K4PITCH];    // 9216 B
    int b  = blockIdx.x;
    int n  = b >> 4;
    int r  = b & 15;
    int c_off  = (r & 7) * 64;
    int hh     = r >> 3;
    int h_base = hh * 512;
    int t = threadIdx.x;
    int l = t & 63, w = t >> 6;
    int mr = l & 15, q = l >> 4;
    int kcb = (w >> 1) * 32, cb = (w & 1) * 32;

    invs[t]       = invn[(long)n * HW_ + h_base + t];
    invs[t + 256] = invn[(long)n * HW_ + h_base + 256 + t];

    f32x4 acc[2][2];
#pragma unroll
    for (int i = 0; i < 2; ++i)
#pragma unroll
        for (int j = 0; j < 2; ++j) acc[i][j] = (f32x4){0.f, 0.f, 0.f, 0.f};

    const unsigned short* Abase = Ab + (long)n * K_ * HW_ + h_base;
    const float* xbase = x + ((long)n * C_ + c_off) * HW_ + h_base;

    for (int ch = 0; ch < 8; ++ch) {
        int h0 = ch * 64;
        __syncthreads();
#pragma unroll
        for (int j = 0; j < 2; ++j) {          // Ash: 64kc x 64h (bf16 copy)
            int idx = j * 256 + t;
            int row = idx >> 3, sg = idx & 7;
            *(uint4*)(Ash + row * K4PITCH + sg * 8) =
                *(const uint4*)(Abase + (long)row * HW_ + h0 + sg * 8);
        }
#pragma unroll
        for (int j = 0; j < 2; ++j) {          // Fsh: 64c x 64h (x*invn -> bf16)
            int idx = j * 256 + t;
            int row = idx >> 3, sg = idx & 7;
            const float* src = xbase + (long)row * HW_ + h0 + sg * 8;
            float4 v0 = *(const float4*)src;
            float4 v1 = *(const float4*)(src + 4);
            const float* iv = invs + h0 + sg * 8;
            ushort8v pk;
            pk[0] = f2bf(v0.x * iv[0]); pk[1] = f2bf(v0.y * iv[1]);
            pk[2] = f2bf(v0.z * iv[2]); pk[3] = f2bf(v0.w * iv[3]);
            pk[4] = f2bf(v1.x * iv[4]); pk[5] = f2bf(v1.y * iv[5]);
            pk[6] = f2bf(v1.z * iv[6]); pk[7] = f2bf(v1.w * iv[7]);
            *(ushort8v*)(Fsh + row * K4PITCH + sg * 8) = pk;
        }
        __syncthreads();
#pragma unroll
        for (int ks = 0; ks < 2; ++ks) {
            int ko = ks * 32 + q * 8;
            const unsigned short* ap0 = Ash + (kcb + mr) * K4PITCH + ko;
            const unsigned short* ap1 = Ash + (kcb + 16 + mr) * K4PITCH + ko;
#pragma unroll
            for (int j = 0; j < 2; ++j) {
                const unsigned short* bp = Fsh + (cb + j * 16 + mr) * K4PITCH + ko;
                acc[0][j] = mfma16(ap0, bp, acc[0][j]);
                acc[1][j] = mfma16(ap1, bp, acc[1][j]);
            }
        }
    }
    float* pb = part + (long)hh * PART_ELEMS + (long)n * K_ * C_ + c_off;
#pragma unroll
    for (int i = 0; i < 2; ++i)
#pragma unroll
        for (int j = 0; j < 2; ++j)
#pragma unroll
            for (int rr = 0; rr < 4; ++rr) {
                int kc = kcb + i * 16 + q * 4 + rr;
                int c  = cb + j * 16 + mr;
                pb[(long)kc * C_ + c] = acc[i][j][rr];
            }
}

// ---------------- K5: combine 2 partials, subtract sumA*W, intra-normalize
__global__ __launch_bounds__(256) void k5_norm(const float* __restrict__ part,
                                               const float* __restrict__ sumA_part,
                                               const float* __restrict__ wT,
                                               float* __restrict__ vlad) {
    __shared__ float red[256];
    __shared__ float sred[16];
    int row = blockIdx.x;        // n*64 + kc
    int kc  = row & 63;
    int n   = row >> 6;
    int t   = threadIdx.x;
    if (t < 16) sred[t] = sumA_part[((long)n * 16 + t) * 64 + kc];
    __syncthreads();
    float sA = 0.f;
#pragma unroll
    for (int i = 0; i < 16; ++i) sA += sred[i];
    long base = (long)row * C_;
    float v0, v1;
    {
        int c = t;
        float s = part[base + c] + part[PART_ELEMS + base + c];
        v0 = s - sA * wT[kc * C_ + c];
    }
    {
        int c = t + 256;
        float s = part[base + c] + part[PART_ELEMS + base + c];
        v1 = s - sA * wT[kc * C_ + c];
    }
    red[t] = v0 * v0 + v1 * v1;
    __syncthreads();
    for (int st = 128; st > 0; st >>= 1) {
        if (t < st) red[t] += red[t + st];
        __syncthreads();
    }
    float inv = 1.f / fmaxf(sqrtf(red[0]), EPS_);
    vlad[base + t]       = v0 * inv;
    vlad[base + t + 256] = v1 * inv;
}

extern "C" void kernel_launch(void* const* d_in, const int* in_sizes, int n_in,
                              void* d_out, int out_size, void* d_ws, size_t ws_size,
                              hipStream_t stream) {
    const float* x    = (const float*)d_in[0];
    const float* W    = (const float*)d_in[1];
    const float* bias = (const float*)d_in[2];
    float* out = (float*)d_out;
    char* wsb  = (char*)d_ws;

    float* wT            = (float*)(wsb + WSB_WT);
    unsigned short* wnTb = (unsigned short*)(wsb + WSB_WNTB);
    float* invn          = (float*)(wsb + WSB_INVN);
    unsigned short* Ab   = (unsigned short*)(wsb + WSB_A);
    float* sumA_part     = (float*)(wsb + WSB_SAP);
    float* part          = (float*)(wsb + WSB_PART);

    float* vlad = out + OUT_VLAD;
    float* sa   = out + OUT_SA;
    float* feat = out + OUT_FEAT;

    hipLaunchKernelGGL(k1_weights,  dim3(64),   dim3(256), 0, stream, W, wT, wnTb);
    hipLaunchKernelGGL(k2_normfeat, dim3(4096), dim3(256), 0, stream, x, out, invn);
    hipLaunchKernelGGL(k3_sa,       dim3(1024), dim3(256), 0, stream, feat, wnTb, bias, sa, Ab, sumA_part);
    hipLaunchKernelGGL(k4_vlad,     dim3(1024), dim3(256), 0, stream, x, invn, Ab, part);
    hipLaunchKernelGGL(k5_norm,     dim3(4096), dim3(256), 0, stream, part, sumA_part, wT, vlad);
}